// Round 8
// baseline (32.172 us; speedup 1.0000x reference)
//
#include <hip/hip_runtime.h>

// DivEncLayer via MFMA — r6 memory pattern + 4-way ILP per iteration.
// Per (b,q): h = elu(x[b,q*8:+8]@W1[q] + b1[q]); LN(h); out = h@W2[q]+b2[q].
// B=16384, Q=128, S=8, U=32.
//
// v_mfma_f32_32x32x16_bf16 operand mapping (validated rounds 2-7):
//   A: lane l, reg j -> A[l&31][j + 8*(l>>5)]
//   B: lane l, reg j -> B[j + 8*(l>>5)][l&31]
//   D: lane l, reg r -> row u=(r&3)+8*(r>>2)+4*(l>>5), col b=l&31
// Packed A-frag: lanes<32 = bf16(W1^T) (k=0..7), lanes>=32 = bf16(W1-hi) (k=8..15).
// B duplicates each row across lane-halves (addressed by u=ln&31):
// D = (whi+wlo)*xhi + C-in, C-in = b1 (fp32 exact). x is bf16-hi only.
// LN+Dense2 folded: out = rsqrt(var+eps)*(dot(e,g2) - mu*G) + C.
//
// Block = 4 waves = 4 consecutive q. 4 iters x 128 rows (4 tiles of 32) =
// 512 contiguous rows/block; 4 independent MFMA+finish chains interleaved per
// iter (ILP to hide exp/fma chain latency). Loop-carried x kept as bf16
// fragments (16 VGPRs, not 64). Grid (32,32) = 1024 blocks.

typedef __attribute__((ext_vector_type(8))) short short8;    // 8 bf16
typedef __attribute__((ext_vector_type(16))) float f32x16;

__device__ __forceinline__ short fbits(__bf16 b) { return __builtin_bit_cast(short, b); }

__device__ __forceinline__ float elu1(float v) {
    return v > 0.f ? v : __expf(v) - 1.f;
}

__device__ __forceinline__ short8 cvt8(const float4& a, const float4& b) {
    short8 r;
    r[0] = fbits((__bf16)a.x); r[1] = fbits((__bf16)a.y);
    r[2] = fbits((__bf16)a.z); r[3] = fbits((__bf16)a.w);
    r[4] = fbits((__bf16)b.x); r[5] = fbits((__bf16)b.y);
    r[6] = fbits((__bf16)b.z); r[7] = fbits((__bf16)b.w);
    return r;
}

__device__ __forceinline__ float finish(const f32x16& acc, const f32x16& g2r,
                                        float G, float C) {
    float sum = 0.f, ss = 0.f, dot = 0.f;
    #pragma unroll
    for (int r = 0; r < 16; ++r) {
        float e = elu1(acc[r]);
        sum += e;
        ss  = fmaf(e, e, ss);
        dot = fmaf(e, g2r[r], dot);
    }
    sum += __shfl_xor(sum, 32);
    ss  += __shfl_xor(ss, 32);
    dot += __shfl_xor(dot, 32);
    float mu  = sum * 0.03125f;
    float var = fmaf(-mu, mu, ss * 0.03125f);
    float inv = rsqrtf(var + 1e-3f);
    return fmaf(inv, fmaf(-mu, G, dot), C);
}

__global__ __launch_bounds__(256, 3) void divenc_mfma(
    const float* __restrict__ x,      // (16384, 1024)
    const float* __restrict__ W1,     // (128, 8, 32)
    const float* __restrict__ b1,     // (128, 32)
    const float* __restrict__ gamma,  // (128, 32)
    const float* __restrict__ beta,   // (128, 32)
    const float* __restrict__ W2,     // (128, 32)
    const float* __restrict__ b2,     // (128,)
    float* __restrict__ out)          // (16384, 128)
{
    __shared__ float lout[2][128 * 5];  // [buf][row*5 + w], padded stride 5

    const int tid  = threadIdx.x;
    const int w    = tid >> 6;
    const int ln   = tid & 63;
    const int u    = ln & 31;
    const int half = ln >> 5;
    const int qt   = blockIdx.y;      // 0..31
    const int q    = qt * 4 + w;
    const int bx   = blockIdx.x;      // 0..31; block covers rows bx*512..+511

    // ---- A-frag: lanes<32 = whi (k=0..7), lanes>=32 = wlo (k=8..15) ----
    short8 wfrag;
    #pragma unroll
    for (int j = 0; j < 8; ++j) {
        float f  = W1[q * 256 + j * 32 + u];
        __bf16 h = (__bf16)f;
        wfrag[j] = half ? fbits((__bf16)(f - (float)h)) : fbits(h);
    }

    // ---- params: biasr (MFMA C-in) + g2r in regs, vector loads ----
    f32x16 biasr, g2r;
    float G, C;
    {
        float gs = 0.f, cs = 0.f;
        #pragma unroll
        for (int c = 0; c < 4; ++c) {
            const int ub = q * 32 + 4 * half + 8 * c;
            float4 b1v = *(const float4*)&b1[ub];
            float4 gav = *(const float4*)&gamma[ub];
            float4 w2v = *(const float4*)&W2[ub];
            float4 bev = *(const float4*)&beta[ub];
            #pragma unroll
            for (int j = 0; j < 4; ++j) {
                float g2 = ((const float*)&gav)[j] * ((const float*)&w2v)[j];
                biasr[4 * c + j] = ((const float*)&b1v)[j];
                g2r[4 * c + j]   = g2;
                gs += g2;
                cs += ((const float*)&bev)[j] * ((const float*)&w2v)[j];
            }
        }
        gs += __shfl_xor(gs, 32);
        cs += __shfl_xor(cs, 32);
        G = gs;
        C = cs + b2[q];
    }

    const float* xq = x + q * 8;

    // ---- prime iter 0: rows bx*512 + t*32 + u, t=0..3, as bf16 frags ----
    short8 xf0, xf1, xf2, xf3;
    {
        const float* p0 = xq + (size_t)(bx * 512 +  0 + u) * 1024;
        const float* p1 = xq + (size_t)(bx * 512 + 32 + u) * 1024;
        const float* p2 = xq + (size_t)(bx * 512 + 64 + u) * 1024;
        const float* p3 = xq + (size_t)(bx * 512 + 96 + u) * 1024;
        xf0 = cvt8(((const float4*)p0)[0], ((const float4*)p0)[1]);
        xf1 = cvt8(((const float4*)p1)[0], ((const float4*)p1)[1]);
        xf2 = cvt8(((const float4*)p2)[0], ((const float4*)p2)[1]);
        xf3 = cvt8(((const float4*)p3)[0], ((const float4*)p3)[1]);
    }

    #pragma unroll 1
    for (int it = 0; it < 4; ++it) {
        const int b0 = bx * 512 + it * 128;

        // issue next-iter loads early (last iter re-reads current; discarded)
        const int bn = (it < 3) ? b0 + 128 : b0;
        const float* pn0 = xq + (size_t)(bn +  0 + u) * 1024;
        const float* pn1 = xq + (size_t)(bn + 32 + u) * 1024;
        const float* pn2 = xq + (size_t)(bn + 64 + u) * 1024;
        const float* pn3 = xq + (size_t)(bn + 96 + u) * 1024;
        float4 na0 = ((const float4*)pn0)[0], nb0 = ((const float4*)pn0)[1];
        float4 na1 = ((const float4*)pn1)[0], nb1 = ((const float4*)pn1)[1];
        float4 na2 = ((const float4*)pn2)[0], nb2 = ((const float4*)pn2)[1];
        float4 na3 = ((const float4*)pn3)[0], nb3 = ((const float4*)pn3)[1];

        // 4 independent MFMA+finish chains, interleaved for ILP
        f32x16 acc0 = __builtin_amdgcn_mfma_f32_32x32x16_bf16(wfrag, xf0, biasr, 0, 0, 0);
        f32x16 acc1 = __builtin_amdgcn_mfma_f32_32x32x16_bf16(wfrag, xf1, biasr, 0, 0, 0);
        float res0 = finish(acc0, g2r, G, C);
        f32x16 acc2 = __builtin_amdgcn_mfma_f32_32x32x16_bf16(wfrag, xf2, biasr, 0, 0, 0);
        float res1 = finish(acc1, g2r, G, C);
        f32x16 acc3 = __builtin_amdgcn_mfma_f32_32x32x16_bf16(wfrag, xf3, biasr, 0, 0, 0);
        float res2 = finish(acc2, g2r, G, C);
        float res3 = finish(acc3, g2r, G, C);

        // stage results (rows t*32+u of this 128-row group, this wave's q)
        if (half == 0) {
            float* lb = lout[it & 1];
            lb[(u +  0) * 5 + w] = res0;
            lb[(u + 32) * 5 + w] = res1;
            lb[(u + 64) * 5 + w] = res2;
            lb[(u + 96) * 5 + w] = res3;
        }

        // convert arrived prefetch -> next iter's frags (gives loads slack)
        xf0 = cvt8(na0, nb0);
        xf1 = cvt8(na1, nb1);
        xf2 = cvt8(na2, nb2);
        xf3 = cvt8(na3, nb3);

        __syncthreads();

        // gather: 128 rows, one float4 store per row (write-exact pattern)
        if (tid < 128) {
            const float* lb = lout[it & 1];
            float4 o;
            o.x = lb[tid * 5 + 0];
            o.y = lb[tid * 5 + 1];
            o.z = lb[tid * 5 + 2];
            o.w = lb[tid * 5 + 3];
            *(float4*)(out + (size_t)(b0 + tid) * 128 + qt * 4) = o;
        }
        // no second barrier: next iter writes the other lout buffer
    }
}

extern "C" void kernel_launch(void* const* d_in, const int* in_sizes, int n_in,
                              void* d_out, int out_size, void* d_ws, size_t ws_size,
                              hipStream_t stream) {
    const float* x     = (const float*)d_in[0];
    const float* W1    = (const float*)d_in[1];
    const float* b1    = (const float*)d_in[2];
    const float* gamma = (const float*)d_in[3];
    const float* beta  = (const float*)d_in[4];
    const float* W2    = (const float*)d_in[5];
    const float* b2    = (const float*)d_in[6];
    float* out = (float*)d_out;

    dim3 grid(32, 32);   // (512-row bands, q-tiles of 4)
    divenc_mfma<<<grid, 256, 0, stream>>>(x, W1, b1, gamma, beta, W2, b2, out);
}